// Round 2
// baseline (76.418 us; speedup 1.0000x reference)
//
#include <hip/hip_runtime.h>
#include <math.h>

// KANLayer: out[b,o] = sum_i C[i,o]*(sum_k basis_k(x[b,i])*W[i,o,k] + bias[i,o])
// R4: SINGLE kernel, zero workspace. Column-sliced blocking (64 rows x 32 cols
// per block, grid 256 = 1/CU) so each block folds its own Weff slice (W*C ->
// bf16) into LDS per K-chunk. Deletes: fold kernel, launch gap, BT HBM/L2
// round-trip. bterm computed per-block via 16-lane shuffle reduction.
// K-chunked: 4 x 288 (32 din x 9 basis). LDS 57 KB single-buffered.

#define DIN   128
#define DOUT  128
#define NB    9
#define KK    (DIN * NB)    // 1152
#define BATCH 4096
#define BR    64            // batch rows per block
#define BC    32            // out cols per block
#define IC    32            // input dims per K-chunk
#define BK    (IC * NB)     // 288 k per chunk
#define NCH   (DIN / IC)    // 4 chunks
#define PAD   8             // bf16 pad -> row stride 148 dwords (=20 mod 32, 2-way free)
#define LSTR  (BK + PAD)    // 296 bf16

typedef __bf16 bf16x8 __attribute__((ext_vector_type(8)));
typedef float  f32x4  __attribute__((ext_vector_type(4)));
typedef unsigned int uint;

__device__ __forceinline__ uint pack2(float lo, float hi) {
    __bf16 l = (__bf16)lo, h = (__bf16)hi;
    unsigned short ul, uh;
    __builtin_memcpy(&ul, &l, 2);
    __builtin_memcpy(&uh, &h, 2);
    return (uint)ul | ((uint)uh << 16);
}

__device__ __forceinline__ void basis9(float v, float* f) {
    const float av = fabsf(v);
    f[0] = v;
    f[1] = v * v;
    f[2] = f[1] * v;
    f[3] = __expf(v);
    f[4] = __logf(av + 1.0f);
    f[5] = __builtin_sqrtf(av);
    // tanh(v) = sign(v)*(1 - e^{-2|v|})/(1 + e^{-2|v|}); err ~1e-7 << bf16 lsb
    const float e2 = __expf(-2.0f * av);
    const float th = (1.0f - e2) * __builtin_amdgcn_rcpf(1.0f + e2);
    f[6] = __builtin_copysignf(th, v);
    f[7] = __sinf(v);
    f[8] = av;
}

// 256 blocks x 512 threads (8 waves). Block: rows rb*64..+63, cols cb*32..+31.
// Wave w -> 16x16 tile (wr = w&3 row-tile, wc = w>>2 col-tile).
// Per chunk: stage As[64][296] (basis, packed dwords) + Bs[32][296] (W*C fold,
// packed dwords), sync, 9 MFMA per wave, sync.
// Layouts (HW-verified): A-frag A[m=lane&15][k=quad*8+j],
// B-frag B[n=lane&15][k=quad*8+j], C/D col=lane&15 row=quad*4+reg.
__global__ __launch_bounds__(512, 1) void kan_kernel(const float* __restrict__ x,
                                                     const float* __restrict__ W,
                                                     const float* __restrict__ bias,
                                                     const float* __restrict__ C,
                                                     float* __restrict__ out) {
    __shared__ __bf16 As[BR * LSTR];   // 37,888 B
    __shared__ __bf16 Bs[BC * LSTR];   // 18,944 B
    __shared__ float  btl[BC];

    const int t    = threadIdx.x;
    const int rb   = blockIdx.x >> 2;  // 0..63
    const int cb   = blockIdx.x & 3;   // 0..3
    const int row0 = rb * BR;
    const int col0 = cb * BC;

    const int lane = t & 63;
    const int wave = t >> 6;           // 0..7
    const int wr   = wave & 3;
    const int wc   = wave >> 2;
    const int m    = lane & 15;
    const int quad = lane >> 4;

    // ---- bterm for this block's 32 cols: t = o_l*16 + ig; ig sums 8 i's ----
    {
        const int o_l = t >> 4;        // 0..31
        const int ig  = t & 15;
        const int o   = col0 + o_l;
        float p = 0.0f;
        #pragma unroll
        for (int s = 0; s < 8; ++s) {
            const int i = ig * 8 + s;
            p += bias[i * DOUT + o] * C[i * DOUT + o];
        }
        // reduce within each 16-lane group (lanes (o_l&3)*16 + ig)
        p += __shfl_down(p, 8);
        p += __shfl_down(p, 4);
        p += __shfl_down(p, 2);
        p += __shfl_down(p, 1);
        if (ig == 0) btl[o_l] = p;     // ordered by the chunk-0 __syncthreads
    }

    f32x4 acc = {0.0f, 0.0f, 0.0f, 0.0f};
    const __bf16* Ap = &As[(wr * 16 + m) * LSTR + quad * 8];
    const __bf16* Bp = &Bs[(wc * 16 + m) * LSTR + quad * 8];

    for (int ck = 0; ck < NCH; ++ck) {
        const int ib0 = ck * IC;       // global input-dim base of this chunk

        // ---- stage A: 64 rows x 32 i = 1024 elem-pairs, 2 per thread ----
        #pragma unroll
        for (int pp = 0; pp < 2; ++pp) {
            const int p  = t + pp * 512;      // 0..1023
            const int r  = p >> 4;            // 0..63
            const int il = (p & 15) * 2;      // even local i
            const float2 xv = *(const float2*)&x[(size_t)(row0 + r) * DIN + ib0 + il];
            float fa[9], fb[9];
            basis9(xv.x, fa);
            basis9(xv.y, fb);
            uint* dst = (uint*)&As[r * LSTR + il * NB];   // dword-aligned (il even)
            dst[0] = pack2(fa[0], fa[1]);
            dst[1] = pack2(fa[2], fa[3]);
            dst[2] = pack2(fa[4], fa[5]);
            dst[3] = pack2(fa[6], fa[7]);
            dst[4] = pack2(fa[8], fb[0]);
            dst[5] = pack2(fb[1], fb[2]);
            dst[6] = pack2(fb[3], fb[4]);
            dst[7] = pack2(fb[5], fb[6]);
            dst[8] = pack2(fb[7], fb[8]);
        }

        // ---- stage B: fold W*C for 32 cols x 32 i; one (col, i-pair)/thread --
        {
            const int o_l = t >> 4;           // 0..31
            const int il  = (t & 15) * 2;     // even local i
            const int i   = ib0 + il;
            const int o   = col0 + o_l;
            const float c0 = C[i * DOUT + o];
            const float c1 = C[(i + 1) * DOUT + o];
            const float* w0 = W + ((size_t)i * DOUT + o) * NB;
            const float* w1 = W + ((size_t)(i + 1) * DOUT + o) * NB;
            float f[18];
            #pragma unroll
            for (int k = 0; k < NB; ++k) f[k]      = w0[k] * c0;
            #pragma unroll
            for (int k = 0; k < NB; ++k) f[NB + k] = w1[k] * c1;
            uint* dst = (uint*)&Bs[o_l * LSTR + il * NB];  // dword-aligned
            #pragma unroll
            for (int j = 0; j < 9; ++j) dst[j] = pack2(f[2 * j], f[2 * j + 1]);
        }

        __syncthreads();

        // ---- MFMA: 9 k-steps of 32 ----
        #pragma unroll
        for (int j = 0; j < BK / 32; ++j) {
            bf16x8 a = *(const bf16x8*)(Ap + j * 32);
            bf16x8 b = *(const bf16x8*)(Bp + j * 32);
            acc = __builtin_amdgcn_mfma_f32_16x16x32_bf16(a, b, acc, 0, 0, 0);
        }

        if (ck + 1 < NCH) __syncthreads();   // protect buffers before restage
    }

    const float bt = btl[wc * 16 + m];
    float* op = out + (size_t)(row0 + wr * 16 + quad * 4) * DOUT + col0 + wc * 16 + m;
    #pragma unroll
    for (int r = 0; r < 4; ++r) op[(size_t)r * DOUT] = acc[r] + bt;
}

// ---------------- launcher ---------------------------------------------------
extern "C" void kernel_launch(void* const* d_in, const int* in_sizes, int n_in,
                              void* d_out, int out_size, void* d_ws, size_t ws_size,
                              hipStream_t stream) {
    const float* x    = (const float*)d_in[0];   // [4096,128]
    const float* W    = (const float*)d_in[1];   // [128,128,9]
    const float* bias = (const float*)d_in[2];   // [128,128]
    const float* C    = (const float*)d_in[3];   // [128,128]
    float* out = (float*)d_out;                  // [4096,128]

    kan_kernel<<<(BATCH / BR) * (DOUT / BC), 512, 0, stream>>>(x, W, bias, C, out);
}

// Round 3
// 71.321 us; speedup vs baseline: 1.0715x; 1.0715x over previous
//
#include <hip/hip_runtime.h>
#include <math.h>

// KANLayer: out[b,o] = sum_i C[i,o]*(sum_k basis_k(x[b,i])*W[i,o,k] + bias[i,o])
// = GEMM: out = feats[4096 x 1152] * Weff[1152 x 128] + bterm[o]
// R5: revert to R3 two-kernel structure (R4 single-kernel regressed: chunked
// barriers exposed fold/global latency). On top of R3:
//   (a) fused stage 1: one float4 load / 4 basis evals per thread (was 2x float2)
//   (b) MFMA loop: first 8 B-fragments prefetched into registers BEFORE the
//       barrier (compiler can't hoist loads across __syncthreads), full unroll
//       so the prefetch array is register-resident (no scratch).

#define DIN   128
#define DOUT  128
#define NB    9
#define KK    (DIN * NB)    // 1152
#define BATCH 4096
#define ROWS  16            // batch rows per block
#define APAD  8             // +8 bf16 -> row stride 580 dwords
#define ASTR  (KK + APAD)   // 1160
#define PF    8             // B-fragment prefetch depth (pre-barrier)

typedef __bf16 bf16x8 __attribute__((ext_vector_type(8)));
typedef float  f32x4  __attribute__((ext_vector_type(4)));
typedef unsigned int uint;

__device__ __forceinline__ uint pack2(float lo, float hi) {
    __bf16 l = (__bf16)lo, h = (__bf16)hi;
    unsigned short ul, uh;
    __builtin_memcpy(&ul, &l, 2);
    __builtin_memcpy(&uh, &h, 2);
    return (uint)ul | ((uint)uh << 16);
}

__device__ __forceinline__ void basis9(float v, float* f) {
    const float av = fabsf(v);
    f[0] = v;
    f[1] = v * v;
    f[2] = f[1] * v;
    f[3] = __expf(v);
    f[4] = __logf(av + 1.0f);
    f[5] = __builtin_sqrtf(av);
    // tanh(v) = sign(v)*(1 - e^{-2|v|})/(1 + e^{-2|v|}); err ~1e-7 << bf16 lsb
    const float e2 = __expf(-2.0f * av);
    const float th = (1.0f - e2) * __builtin_amdgcn_rcpf(1.0f + e2);
    f[6] = __builtin_copysignf(th, v);
    f[7] = __sinf(v);
    f[8] = av;
}

// ---------------- kernel 1: fold W*C -> BT (bf16, transposed) + bterm --------
// blocks 0..31 : 8192 threads, each folds TWO edges (i,i+1) for one o ->
//                36 B contiguous W reads per thread, 9 packed dword BT writes.
// blocks 32..159: block b handles o=b-32; 128 parallel bias*C loads + shuffle
//                reduction.
__global__ __launch_bounds__(256) void fold_kernel(const float* __restrict__ W,
                                                   const float* __restrict__ bias,
                                                   const float* __restrict__ C,
                                                   __bf16* __restrict__ BT,
                                                   float* __restrict__ bterm) {
    const int b = blockIdx.x;
    const int t = threadIdx.x;

    if (b < 32) {
        const int e2 = b * 256 + t;     // 0..8191
        const int o  = e2 >> 6;         // 0..127 (uniform per wave)
        const int ip = e2 & 63;
        const int i  = ip * 2;

        const float c0 = C[i * DOUT + o];
        const float c1 = C[(i + 1) * DOUT + o];
        const float* w0 = W + ((size_t)i * DOUT + o) * NB;
        const float* w1 = W + ((size_t)(i + 1) * DOUT + o) * NB;

        float f[18];
        #pragma unroll
        for (int k = 0; k < NB; ++k) f[k]      = w0[k] * c0;
        #pragma unroll
        for (int k = 0; k < NB; ++k) f[NB + k] = w1[k] * c1;

        uint* dst = (uint*)(BT + (size_t)o * KK + i * NB);
        #pragma unroll
        for (int j = 0; j < 9; ++j) dst[j] = pack2(f[2 * j], f[2 * j + 1]);
    } else {
        const int o = b - 32;           // 0..127
        float p = 0.0f;
        if (t < DIN) p = bias[t * DOUT + o] * C[t * DOUT + o];
        p += __shfl_down(p, 32);
        p += __shfl_down(p, 16);
        p += __shfl_down(p, 8);
        p += __shfl_down(p, 4);
        p += __shfl_down(p, 2);
        p += __shfl_down(p, 1);
        __shared__ float red[4];
        if ((t & 63) == 0) red[t >> 6] = p;
        __syncthreads();
        if (t == 0) bterm[o] = red[0] + red[1] + red[2] + red[3];
    }
}

// ---------------- kernel 2: fused basis expansion + MFMA GEMM ----------------
// 256 blocks x 512 threads (8 waves). Block: 16 batch rows x all 128 cols.
// Stage 1: each thread loads float4 (4 x-values) -> 4 basis evals -> 18 packed
//          dwords into LDS As[16][1160] bf16 (stride 18 dwords, 2-way free).
// Stage 2: wave w computes the 16x16 tile at cols w*16; A-frags from LDS,
//          B-frags from global (BT = 294 KB, L2-resident). First PF B-frags
//          are register-prefetched before the barrier.
// Layouts (HW-verified): A-frag A[m=lane&15][k=quad*8+j],
// B-frag BT[n=lane&15][k=quad*8+j], C/D col=lane&15 row=quad*4+reg.
__global__ __launch_bounds__(512, 1) void fused_kernel(const float* __restrict__ x,
                                                       const __bf16* __restrict__ BT,
                                                       const float* __restrict__ bterm,
                                                       float* __restrict__ out) {
    __shared__ __bf16 As[ROWS * ASTR];   // 37120 B
    const int t    = threadIdx.x;
    const int row0 = blockIdx.x * ROWS;

    const int lane = t & 63;
    const int wave = t >> 6;             // 0..7 -> col tile
    const int m    = lane & 15;
    const int quad = lane >> 4;
    const int col0 = wave << 4;

    // hoisted: bterm + B prefetch (issued before stage 1 VALU, in flight early)
    const float bt = bterm[col0 + m];
    const __bf16* Bp = BT + (size_t)(col0 + m) * KK + quad * 8;

    bf16x8 bpre[PF];
    #pragma unroll
    for (int j = 0; j < PF; ++j) bpre[j] = *(const bf16x8*)(Bp + j * 32);

    // ---- stage 1: basis expansion into LDS (float4 -> 4 evals -> 18 dwords) -
    {
        const int r  = t >> 5;           // row within tile 0..15
        const int il = (t & 31) * 4;     // din index, multiple of 4
        const float4 xv = *(const float4*)&x[(size_t)(row0 + r) * DIN + il];
        float f[36];
        basis9(xv.x, f);
        basis9(xv.y, f + 9);
        basis9(xv.z, f + 18);
        basis9(xv.w, f + 27);
        uint* dst = (uint*)&As[r * ASTR + il * NB];   // 72 B contiguous, aligned
        #pragma unroll
        for (int j = 0; j < 18; ++j) dst[j] = pack2(f[2 * j], f[2 * j + 1]);
    }
    __syncthreads();

    // ---- stage 2: MFMA, fully unrolled; first PF iters use prefetched B ----
    const __bf16* Ap = &As[m * ASTR + quad * 8];

    f32x4 acc = {0.0f, 0.0f, 0.0f, 0.0f};

    #pragma unroll
    for (int kc = 0; kc < KK / 32; ++kc) {   // 36 iters, static indices
        bf16x8 a = *(const bf16x8*)(Ap + kc * 32);
        bf16x8 b = (kc < PF) ? bpre[kc] : *(const bf16x8*)(Bp + kc * 32);
        acc = __builtin_amdgcn_mfma_f32_16x16x32_bf16(a, b, acc, 0, 0, 0);
    }

    float* op = out + (size_t)(row0 + quad * 4) * DOUT + col0 + m;
    #pragma unroll
    for (int r = 0; r < 4; ++r) op[(size_t)r * DOUT] = acc[r] + bt;
}

// ---------------- launcher ---------------------------------------------------
extern "C" void kernel_launch(void* const* d_in, const int* in_sizes, int n_in,
                              void* d_out, int out_size, void* d_ws, size_t ws_size,
                              hipStream_t stream) {
    const float* x    = (const float*)d_in[0];   // [4096,128]
    const float* W    = (const float*)d_in[1];   // [128,128,9]
    const float* bias = (const float*)d_in[2];   // [128,128]
    const float* C    = (const float*)d_in[3];   // [128,128]
    float* out = (float*)d_out;                  // [4096,128]

    char* ws = (char*)d_ws;
    __bf16* BT    = (__bf16*)ws;                              // 128*1152*2 = 294,912 B
    float*  bterm = (float*)(ws + (size_t)DOUT * KK * 2);     // 512 B

    fold_kernel<<<160, 256, 0, stream>>>(W, bias, C, BT, bterm);
    fused_kernel<<<BATCH / ROWS, 512, 0, stream>>>(x, BT, bterm, out);
}